// Round 9
// baseline (1641.843 us; speedup 1.0000x reference)
//
#include <hip/hip_runtime.h>
#include <cstdint>
#include <cstddef>

#define SDIM 96
#define BDIM 4
#define NROWS (BDIM * SDIM * SDIM)   // 36864
#define BSROWS (BDIM * SDIM)         // 384
#define DIN 768
#define DOUT 256

typedef short s16x8 __attribute__((ext_vector_type(8)));
typedef float f32x4 __attribute__((ext_vector_type(4)));
typedef unsigned short ushort_t;
typedef unsigned int uint_t;

// ---------------------------------------------------------------------------
// helpers
// ---------------------------------------------------------------------------
__device__ __forceinline__ float sigmoid_f(float x) { return 1.0f / (1.0f + expf(-x)); }

// fp32 -> bf16 RNE
__device__ __forceinline__ ushort_t f2bf(float x) {
    uint_t u = __float_as_uint(x);
    u = u + 0x7fffu + ((u >> 16) & 1u);
    return (ushort_t)(u >> 16);
}
__device__ __forceinline__ float bf2f(ushort_t h) {
    return __uint_as_float(((uint_t)h) << 16);
}

__device__ __forceinline__ void split_store(float x, ushort_t* __restrict__ ph,
                                            ushort_t* __restrict__ pl) {
    ushort_t h = f2bf(x);
    *ph = h;
    *pl = f2bf(x - bf2f(h));
}

// async global->LDS, 16B per lane. ldsptr must be wave-uniform; gptr per-lane.
__device__ __forceinline__ void load_lds16(const void* g, void* l) {
    __builtin_amdgcn_global_load_lds((const __attribute__((address_space(1))) uint_t*)g,
                                     (__attribute__((address_space(3))) uint_t*)l, 16, 0, 0);
}

// ---------------------------------------------------------------------------
// dep_weights[b,i,j] = sigmoid(dep_emb[type] . att_w + att_b) * dep_matrix
// ---------------------------------------------------------------------------
__global__ __launch_bounds__(256) void depw_k(const int* __restrict__ types,
                                              const float* __restrict__ dmat,
                                              const float* __restrict__ emb,
                                              const float* __restrict__ aw,
                                              const float* __restrict__ ab,
                                              float* __restrict__ Wd) {
    int idx = blockIdx.x * 256 + threadIdx.x;
    if (idx >= NROWS) return;
    int t = types[idx];
    float s = ab[0];
#pragma unroll
    for (int k = 0; k < 6; ++k) s = fmaf(emb[t * 6 + k], aw[k], s);
    Wd[idx] = dmat[idx] * sigmoid_f(s);
}

// ---------------------------------------------------------------------------
// weight split+transpose: W[K][N] fp32 -> TH/TL[N][K] bf16 hi/lo
// ---------------------------------------------------------------------------
__global__ __launch_bounds__(256) void splitT_k(const float* __restrict__ W,
                                                ushort_t* __restrict__ TH,
                                                ushort_t* __restrict__ TL, int K, int N) {
    int k = blockIdx.x * 256 + threadIdx.x;
    int n = blockIdx.y;
    if (k >= K) return;
    float x = W[(size_t)k * N + n];
    split_store(x, &TH[(size_t)n * K + k], &TL[(size_t)n * K + k]);
}

// ---------------------------------------------------------------------------
// h_in[b,i,d] = sum_j W[b,i,j]*h[b,i,j,d]; writes fp32 + bf16 hi/lo
// ---------------------------------------------------------------------------
__global__ __launch_bounds__(256) void rowsum_k(const float* __restrict__ h,
                                                const float* __restrict__ W,
                                                float* __restrict__ hinF,
                                                ushort_t* __restrict__ hinH,
                                                ushort_t* __restrict__ hinL) {
    int d = blockIdx.x * 256 + threadIdx.x;  // < 768
    int bi = blockIdx.y;                     // b*S+i
    const float* hp = h + (size_t)bi * SDIM * DIN + d;
    const float* wp = W + bi * SDIM;
    float acc = 0.f;
#pragma unroll 8
    for (int j = 0; j < SDIM; ++j) acc = fmaf(wp[j], hp[(size_t)j * DIN], acc);
    size_t o = (size_t)bi * DIN + d;
    hinF[o] = acc;
    split_store(acc, &hinH[o], &hinL[o]);
}

__global__ __launch_bounds__(256) void colsum_k(const float* __restrict__ h,
                                                const float* __restrict__ W,
                                                float* __restrict__ houtF,
                                                ushort_t* __restrict__ houtH,
                                                ushort_t* __restrict__ houtL) {
    int d = blockIdx.x * 256 + threadIdx.x;
    int bj = blockIdx.y;  // b*S + j
    int b = bj / SDIM;
    int j = bj - b * SDIM;
    const float* hp = h + ((size_t)(b * SDIM) * SDIM + j) * DIN + d;
    const float* wp = W + (size_t)(b * SDIM) * SDIM + j;
    float acc = 0.f;
#pragma unroll 8
    for (int i = 0; i < SDIM; ++i)
        acc = fmaf(wp[(size_t)i * SDIM], hp[(size_t)i * SDIM * DIN], acc);
    size_t o = (size_t)bj * DIN + d;
    houtF[o] = acc;
    split_store(acc, &houtH[o], &houtL[o]);
}

// ---------------------------------------------------------------------------
// sem stencil; output split bf16 hi/lo (feeds gate GEMM A operand)
// ---------------------------------------------------------------------------
__global__ __launch_bounds__(256) void sem_k(const float* __restrict__ h,
                                             const float* __restrict__ a_simi,
                                             const float* __restrict__ t_simi,
                                             ushort_t* __restrict__ semH,
                                             ushort_t* __restrict__ semL) {
    int idx = blockIdx.x * 256 + threadIdx.x;  // < NROWS*192
    int d4 = idx % 192;
    int m = idx / 192;
    int j = m % SDIM;
    int r = m / SDIM;
    int i = r % SDIM;
    int b = r / SDIM;
    const float4* h4 = (const float4*)h;
    float4 acc = h4[(size_t)m * 192 + d4];
    if (j > 0) {
        float t = t_simi[b * SDIM + j - 1];
        float4 v = h4[(size_t)(m - 1) * 192 + d4];
        acc.x = fmaf(t, v.x, acc.x); acc.y = fmaf(t, v.y, acc.y);
        acc.z = fmaf(t, v.z, acc.z); acc.w = fmaf(t, v.w, acc.w);
    }
    if (j < SDIM - 1) {
        float t = t_simi[b * SDIM + j + 1];
        float4 v = h4[(size_t)(m + 1) * 192 + d4];
        acc.x = fmaf(t, v.x, acc.x); acc.y = fmaf(t, v.y, acc.y);
        acc.z = fmaf(t, v.z, acc.z); acc.w = fmaf(t, v.w, acc.w);
    }
    if (i > 0) {
        float a = a_simi[b * SDIM + i - 1];
        float4 v = h4[(size_t)(m - SDIM) * 192 + d4];
        acc.x = fmaf(a, v.x, acc.x); acc.y = fmaf(a, v.y, acc.y);
        acc.z = fmaf(a, v.z, acc.z); acc.w = fmaf(a, v.w, acc.w);
    }
    if (i < SDIM - 1) {
        float a = a_simi[b * SDIM + i + 1];
        float4 v = h4[(size_t)(m + SDIM) * 192 + d4];
        acc.x = fmaf(a, v.x, acc.x); acc.y = fmaf(a, v.y, acc.y);
        acc.z = fmaf(a, v.z, acc.z); acc.w = fmaf(a, v.w, acc.w);
    }
    size_t o = (size_t)m * DIN + d4 * 4;
    ushort_t hh[4], ll[4];
    float vv[4] = {acc.x, acc.y, acc.z, acc.w};
#pragma unroll
    for (int e = 0; e < 4; ++e) {
        hh[e] = f2bf(vv[e]);
        ll[e] = f2bf(vv[e] - bf2f(hh[e]));
    }
    *(ushort4*)&semH[o] = make_ushort4(hh[0], hh[1], hh[2], hh[3]);
    *(ushort4*)&semL[o] = make_ushort4(ll[0], ll[1], ll[2], ll[3]);
}

// ---------------------------------------------------------------------------
// Split-bf16 MFMA GEMM: C(MxN) = (AH+AL)(MxK) @ (BH+BL)^T-stored(NxK)
// 3 MFMA per pair (hh + hl + lh), fp32 accum.
// Tile 256x128, BK=32, 512 threads = 8 waves (4m x 2n), each wave 64x64 out.
// LDS single-buffered 48 KB; per-chunk [4 k-slices][16 rows][16B] layout so
// staging AND frag reads are base + lane*16 (verified 0 bank conflicts).
// 2-barrier loop; 2 blocks/CU -> 16 waves/CU for latency hiding.
// EPI 0: C = acc + bias  (fp32 out)
// EPI 1: gate fusion (bias = gate_b): logit = acc + Pin + Pout + bias;
//        C = g*sem + (1-g)*syn + hprev  -> XH/XL bf16 hi/lo
// ---------------------------------------------------------------------------
template <int EPI>
__global__ __launch_bounds__(512) void gemm_mfma(
    const ushort_t* __restrict__ AH, const ushort_t* __restrict__ AL,
    const ushort_t* __restrict__ BH, const ushort_t* __restrict__ BL,  // [N][K]
    int M, int N, int K, int nbx,
    float* __restrict__ C, const float* __restrict__ bias,
    ushort_t* __restrict__ XH, ushort_t* __restrict__ XL,
    const float* __restrict__ Pin, const float* __restrict__ Pout,
    const float* __restrict__ hin, const float* __restrict__ hout,
    const float* __restrict__ hprev) {
    // A: 16 chunks x 512 ushorts (256 rows x 32k); B: 8 chunks (128 rows x 32k)
    __shared__ __align__(16) ushort_t Ash[8192];
    __shared__ __align__(16) ushort_t Asl[8192];
    __shared__ __align__(16) ushort_t Bsh[4096];
    __shared__ __align__(16) ushort_t Bsl[4096];

    // bijective XCD-aware swizzle (m204 form; works for any nwg)
    const int nwg = gridDim.x;
    const int orig = blockIdx.x;
    const int qq = nwg >> 3, rr = nwg & 7;
    const int xcd = orig & 7, sidx = orig >> 3;
    const int swz = (xcd < rr ? xcd * (qq + 1) : rr * (qq + 1) + (xcd - rr) * qq) + sidx;
    const int bx = swz % nbx;
    const int by = swz / nbx;
    const int bm = by * 256, bn = bx * 128;

    const int tid = threadIdx.x;
    const int wave = tid >> 6, lane = tid & 63;
    const int lq = lane & 15;            // row within 16-row chunk
    const int lg = lane >> 4;            // k-slice (8 ushorts)
    const int wm = wave >> 1, wn = wave & 1;   // 4 x 2 wave grid

    f32x4 acc[4][4];
#pragma unroll
    for (int a = 0; a < 4; ++a)
#pragma unroll
        for (int b = 0; b < 4; ++b) acc[a][b] = (f32x4){0.f, 0.f, 0.f, 0.f};

    const int nt = K >> 5;  // K/32 tiles

    // per-wave staging: A chunks {wave, wave+8} (hi+lo) + B chunk {wave} (hi+lo)
#define STAGE(k0)                                                                   \
    {                                                                               \
        _Pragma("unroll") for (int cc = 0; cc < 2; ++cc) {                          \
            const int c = wave + cc * 8;                                            \
            const int row = c * 16 + lq;                                            \
            const size_t ga = (size_t)(bm + row) * K + (k0) + lg * 8;               \
            load_lds16(AH + ga, &Ash[c * 512]);                                     \
            load_lds16(AL + ga, &Asl[c * 512]);                                     \
        }                                                                           \
        {                                                                           \
            const int rowb = wave * 16 + lq;                                        \
            const size_t gb = (size_t)(bn + rowb) * K + (k0) + lg * 8;              \
            load_lds16(BH + gb, &Bsh[wave * 512]);                                  \
            load_lds16(BL + gb, &Bsl[wave * 512]);                                  \
        }                                                                           \
    }

    for (int t = 0; t < nt; ++t) {
        STAGE(t * 32);
        __syncthreads();  // drains vmcnt(0): staged tile visible to all waves

        s16x8 ah[4], al[4], bh[4], bl[4];
#pragma unroll
        for (int f = 0; f < 4; ++f) {
            const int cA = (wm * 4 + f) * 512 + lane * 8;
            const int cB = (wn * 4 + f) * 512 + lane * 8;
            ah[f] = *(const s16x8*)&Ash[cA];
            al[f] = *(const s16x8*)&Asl[cA];
            bh[f] = *(const s16x8*)&Bsh[cB];
            bl[f] = *(const s16x8*)&Bsl[cB];
        }
        __builtin_amdgcn_s_setprio(1);
#pragma unroll
        for (int mf = 0; mf < 4; ++mf)
#pragma unroll
            for (int nf = 0; nf < 4; ++nf) {
                acc[mf][nf] = __builtin_amdgcn_mfma_f32_16x16x32_bf16(ah[mf], bh[nf], acc[mf][nf], 0, 0, 0);
                acc[mf][nf] = __builtin_amdgcn_mfma_f32_16x16x32_bf16(ah[mf], bl[nf], acc[mf][nf], 0, 0, 0);
                acc[mf][nf] = __builtin_amdgcn_mfma_f32_16x16x32_bf16(al[mf], bh[nf], acc[mf][nf], 0, 0, 0);
            }
        __builtin_amdgcn_s_setprio(0);
        __syncthreads();  // frag ds_reads drained before next STAGE overwrites
    }
#undef STAGE

    // epilogue. C/D layout (HW-verified m89): col = lane&15, row = (lane>>4)*4 + reg
#pragma unroll
    for (int mf = 0; mf < 4; ++mf) {
#pragma unroll
        for (int jj = 0; jj < 4; ++jj) {
            const int gr = bm + wm * 64 + mf * 16 + lg * 4 + jj;
            int ri = 0, rj = 0;
            if (EPI == 1) {
                const int b_ = gr / 9216;
                const int rem = gr - b_ * 9216;
                const int i_ = rem / 96;
                const int j_ = rem - i_ * 96;
                ri = (b_ * 96 + i_) * 768;
                rj = (b_ * 96 + j_) * 768;
            }
#pragma unroll
            for (int nf = 0; nf < 4; ++nf) {
                const int gc = bn + wn * 64 + nf * 16 + lq;
                float v = acc[mf][nf][jj];
                if (EPI == 0) {
                    if (bias != nullptr) v += bias[gc];
                    C[(size_t)gr * N + gc] = v;
                } else {
                    const float gte = sigmoid_f(v + Pin[ri + gc] + Pout[rj + gc] + bias[gc]);
                    const float syn = hin[ri + gc] + hout[rj + gc];
                    const size_t o = (size_t)gr * 768 + gc;
                    const float sem = bf2f(AH[o]) + bf2f(AL[o]);
                    const float x = fmaf(gte, sem - syn, syn) + hprev[o];
                    split_store(x, &XH[o], &XL[o]);
                }
            }
        }
    }
}

// ---------------------------------------------------------------------------
// T5 layernorm (+relu): out = max(0, x * rsqrt(mean(x^2)+eps) * w), per row
// ---------------------------------------------------------------------------
template <int D>
__global__ __launch_bounds__(256) void norm_relu_k(const float* __restrict__ Y,
                                                   const float* __restrict__ w,
                                                   float* __restrict__ out) {
    constexpr int E = D / 256;
    int row = blockIdx.x;
    int tid = threadIdx.x;
    float v[E];
    float ss = 0.f;
#pragma unroll
    for (int e = 0; e < E; ++e) {
        v[e] = Y[(size_t)row * D + e * 256 + tid];
        ss = fmaf(v[e], v[e], ss);
    }
#pragma unroll
    for (int off = 32; off >= 1; off >>= 1) ss += __shfl_down(ss, off);
    __shared__ float red[4];
    int lane = tid & 63;
    int wid = tid >> 6;
    if (lane == 0) red[wid] = ss;
    __syncthreads();
    float tot = red[0] + red[1] + red[2] + red[3];
    float scale = rsqrtf(tot / (float)D + 1e-12f);
#pragma unroll
    for (int e = 0; e < E; ++e) {
        float o = v[e] * scale * w[e * 256 + tid];
        out[(size_t)row * D + e * 256 + tid] = fmaxf(o, 0.f);
    }
}

// ---------------------------------------------------------------------------
// launch
// ---------------------------------------------------------------------------
extern "C" void kernel_launch(void* const* d_in, const int* in_sizes, int n_in,
                              void* d_out, int out_size, void* d_ws, size_t ws_size,
                              hipStream_t stream) {
    (void)in_sizes; (void)n_in; (void)out_size; (void)ws_size;
    const float* table = (const float*)d_in[0];
    const float* a_simi = (const float*)d_in[1];
    const float* t_simi = (const float*)d_in[2];
    const float* dep_matrix = (const float*)d_in[3];
    const int* dep_types = (const int*)d_in[4];
    const float* d1w = (const float*)d_in[5];
    const float* d1b = (const float*)d_in[6];
    const float* d2w = (const float*)d_in[7];
    const float* d2b = (const float*)d_in[8];
    const float* dep_emb = (const float*)d_in[9];
    const float* att_w = (const float*)d_in[10];
    const float* att_b = (const float*)d_in[11];
    const float* gate_w = (const float*)d_in[12];
    const float* gate_b = (const float*)d_in[13];
    const float* nw1 = (const float*)d_in[14];
    const float* nw2 = (const float*)d_in[15];
    float* out = (float*)d_out;

    // ---- workspace layout (all 16B-aligned offsets) ----
    char* ws = (char*)d_ws;
    size_t off = 0;
    float* Wd = (float*)(ws + off); off += 147456;
    float* hinF = (float*)(ws + off); off += 1179648;
    float* houtF = (float*)(ws + off); off += 1179648;
    float* Pfull = (float*)(ws + off); off += 2359296;          // 768 x 768 fp32
    ushort_t* hioH = (ushort_t*)(ws + off); off += 1179648;     // 768 x 768 bf16 (hin rows 0..383, hout 384..767)
    ushort_t* hioL = (ushort_t*)(ws + off); off += 1179648;
    ushort_t* GtopTH = (ushort_t*)(ws + off); off += 1179648;
    ushort_t* GtopTL = (ushort_t*)(ws + off); off += 1179648;
    ushort_t* GbotTH = (ushort_t*)(ws + off); off += 1179648;
    ushort_t* GbotTL = (ushort_t*)(ws + off); off += 1179648;
    ushort_t* D1TH = (ushort_t*)(ws + off); off += 1179648;
    ushort_t* D1TL = (ushort_t*)(ws + off); off += 1179648;
    ushort_t* D2TH = (ushort_t*)(ws + off); off += 393216;
    ushort_t* D2TL = (ushort_t*)(ws + off); off += 393216;
    char* P1 = ws + off; off += 113246208;  // sem1 H/L -> Y1 fp32 -> X2 H/L
    char* P2 = ws + off; off += 113246208;  // X1 H/L -> sem2 H/L
    char* P3 = ws + off; off += 113246208;  // h1 fp32 -> Y2 fp32

    const size_t HALF = 56623104;  // 36864*768*2 bytes
    ushort_t* S1H = (ushort_t*)P1;            ushort_t* S1L = (ushort_t*)(P1 + HALF);
    ushort_t* X1H = (ushort_t*)P2;            ushort_t* X1L = (ushort_t*)(P2 + HALF);
    float* Y1 = (float*)P1;
    float* h1 = (float*)P3;
    ushort_t* S2H = (ushort_t*)P2;            ushort_t* S2L = (ushort_t*)(P2 + HALF);
    ushort_t* X2H = (ushort_t*)P1;            ushort_t* X2L = (ushort_t*)(P1 + HALF);
    float* Y2 = (float*)P3;

    float* Pin = Pfull;                       // rows 0..383
    float* Pout = Pfull + (size_t)BSROWS * DIN;  // rows 384..767

    const dim3 blk(256);
    const dim3 blk512(512);
    const dim3 gSplit768(3, 768);
    const dim3 gSplit256(3, 256);
    const dim3 gRS(DIN / 256, BSROWS);
    const int gSem = (NROWS * (DIN / 4)) / 256;
    const int gBig = (NROWS / 256) * (DIN / 128);   // 144*6 = 864
    const int gD2g = (NROWS / 256) * (DOUT / 128);  // 144*2 = 288
    const int gP = (2 * BSROWS / 256) * (DIN / 128);  // 3*6 = 18

    // dep weights + weight split/transpose (weights: [K][N] -> [N][K] hi/lo)
    depw_k<<<NROWS / 256, blk, 0, stream>>>(dep_types, dep_matrix, dep_emb, att_w, att_b, Wd);
    splitT_k<<<gSplit768, blk, 0, stream>>>(gate_w, GtopTH, GtopTL, DIN, DIN);
    splitT_k<<<gSplit768, blk, 0, stream>>>(gate_w + (size_t)DIN * DIN, GbotTH, GbotTL, DIN, DIN);
    splitT_k<<<gSplit768, blk, 0, stream>>>(d1w, D1TH, D1TL, DIN, DIN);
    splitT_k<<<gSplit256, blk, 0, stream>>>(d2w, D2TH, D2TL, DIN, DOUT);

    // ---------------- layer 1 (input: table) ----------------
    rowsum_k<<<gRS, blk, 0, stream>>>(table, Wd, hinF, hioH, hioL);
    colsum_k<<<gRS, blk, 0, stream>>>(table, Wd, houtF, hioH + (size_t)BSROWS * DIN,
                                      hioL + (size_t)BSROWS * DIN);
    sem_k<<<gSem, blk, 0, stream>>>(table, a_simi, t_simi, S1H, S1L);
    // fused P GEMM: [hin; hout] (768 rows) @ Wbot -> Pfull
    gemm_mfma<0><<<gP, blk512, 0, stream>>>(hioH, hioL, GbotTH, GbotTL, 2 * BSROWS, DIN, DIN, DIN / 128,
                                            Pfull, nullptr, nullptr, nullptr, nullptr, nullptr, nullptr, nullptr, nullptr);
    // gate GEMM + fusion -> X1 (bias = gate_b applied in epilogue)
    gemm_mfma<1><<<gBig, blk512, 0, stream>>>(S1H, S1L, GtopTH, GtopTL, NROWS, DIN, DIN, DIN / 128,
                                              nullptr, gate_b, X1H, X1L, Pin, Pout, hinF, houtF, table);
    // dense1 + bias -> Y1
    gemm_mfma<0><<<gBig, blk512, 0, stream>>>(X1H, X1L, D1TH, D1TL, NROWS, DIN, DIN, DIN / 128,
                                              Y1, d1b, nullptr, nullptr, nullptr, nullptr, nullptr, nullptr, nullptr);
    norm_relu_k<DIN><<<NROWS, blk, 0, stream>>>(Y1, nw1, h1);

    // ---------------- layer 2 (input: h1) ----------------
    rowsum_k<<<gRS, blk, 0, stream>>>(h1, Wd, hinF, hioH, hioL);
    colsum_k<<<gRS, blk, 0, stream>>>(h1, Wd, houtF, hioH + (size_t)BSROWS * DIN,
                                      hioL + (size_t)BSROWS * DIN);
    sem_k<<<gSem, blk, 0, stream>>>(h1, a_simi, t_simi, S2H, S2L);
    gemm_mfma<0><<<gP, blk512, 0, stream>>>(hioH, hioL, GbotTH, GbotTL, 2 * BSROWS, DIN, DIN, DIN / 128,
                                            Pfull, nullptr, nullptr, nullptr, nullptr, nullptr, nullptr, nullptr, nullptr);
    gemm_mfma<1><<<gBig, blk512, 0, stream>>>(S2H, S2L, GtopTH, GtopTL, NROWS, DIN, DIN, DIN / 128,
                                              nullptr, gate_b, X2H, X2L, Pin, Pout, hinF, houtF, h1);
    // dense2 + bias -> Y2 (N=256)
    gemm_mfma<0><<<gD2g, blk512, 0, stream>>>(X2H, X2L, D2TH, D2TL, NROWS, DOUT, DIN, DOUT / 128,
                                              Y2, d2b, nullptr, nullptr, nullptr, nullptr, nullptr, nullptr, nullptr);
    norm_relu_k<DOUT><<<NROWS, blk, 0, stream>>>(Y2, nw2, out);
}

// Round 11
// 1250.605 us; speedup vs baseline: 1.3128x; 1.3128x over previous
//
#include <hip/hip_runtime.h>
#include <cstdint>
#include <cstddef>

#define SDIM 96
#define BDIM 4
#define NROWS (BDIM * SDIM * SDIM)   // 36864
#define BSROWS (BDIM * SDIM)         // 384
#define DIN 768
#define DOUT 256

typedef short s16x8 __attribute__((ext_vector_type(8)));
typedef float f32x4 __attribute__((ext_vector_type(4)));
typedef unsigned short ushort_t;
typedef unsigned int uint_t;

// ---------------------------------------------------------------------------
// helpers
// ---------------------------------------------------------------------------
__device__ __forceinline__ float sigmoid_f(float x) { return 1.0f / (1.0f + expf(-x)); }

// fp32 -> bf16 RNE
__device__ __forceinline__ ushort_t f2bf(float x) {
    uint_t u = __float_as_uint(x);
    u = u + 0x7fffu + ((u >> 16) & 1u);
    return (ushort_t)(u >> 16);
}
__device__ __forceinline__ float bf2f(ushort_t h) {
    return __uint_as_float(((uint_t)h) << 16);
}

__device__ __forceinline__ void split_store(float x, ushort_t* __restrict__ ph,
                                            ushort_t* __restrict__ pl) {
    ushort_t h = f2bf(x);
    *ph = h;
    *pl = f2bf(x - bf2f(h));
}

// async global->LDS, 16B per lane. ldsptr must be wave-uniform; gptr per-lane.
__device__ __forceinline__ void load_lds16(const void* g, void* l) {
    __builtin_amdgcn_global_load_lds((const __attribute__((address_space(1))) uint_t*)g,
                                     (__attribute__((address_space(3))) uint_t*)l, 16, 0, 0);
}

// ---------------------------------------------------------------------------
// dep_weights[b,i,j] = sigmoid(dep_emb[type] . att_w + att_b) * dep_matrix
// ---------------------------------------------------------------------------
__global__ __launch_bounds__(256) void depw_k(const int* __restrict__ types,
                                              const float* __restrict__ dmat,
                                              const float* __restrict__ emb,
                                              const float* __restrict__ aw,
                                              const float* __restrict__ ab,
                                              float* __restrict__ Wd) {
    int idx = blockIdx.x * 256 + threadIdx.x;
    if (idx >= NROWS) return;
    int t = types[idx];
    float s = ab[0];
#pragma unroll
    for (int k = 0; k < 6; ++k) s = fmaf(emb[t * 6 + k], aw[k], s);
    Wd[idx] = dmat[idx] * sigmoid_f(s);
}

// ---------------------------------------------------------------------------
// weight split+transpose: W[K][N] fp32 -> TH/TL[N][K] bf16 hi/lo
// ---------------------------------------------------------------------------
__global__ __launch_bounds__(256) void splitT_k(const float* __restrict__ W,
                                                ushort_t* __restrict__ TH,
                                                ushort_t* __restrict__ TL, int K, int N) {
    int k = blockIdx.x * 256 + threadIdx.x;
    int n = blockIdx.y;
    if (k >= K) return;
    float x = W[(size_t)k * N + n];
    split_store(x, &TH[(size_t)n * K + k], &TL[(size_t)n * K + k]);
}

// ---------------------------------------------------------------------------
// h_in[b,i,d] = sum_j W[b,i,j]*h[b,i,j,d]; writes fp32 + bf16 hi/lo
// ---------------------------------------------------------------------------
__global__ __launch_bounds__(256) void rowsum_k(const float* __restrict__ h,
                                                const float* __restrict__ W,
                                                float* __restrict__ hinF,
                                                ushort_t* __restrict__ hinH,
                                                ushort_t* __restrict__ hinL) {
    int d = blockIdx.x * 256 + threadIdx.x;  // < 768
    int bi = blockIdx.y;                     // b*S+i
    const float* hp = h + (size_t)bi * SDIM * DIN + d;
    const float* wp = W + bi * SDIM;
    float acc = 0.f;
#pragma unroll 8
    for (int j = 0; j < SDIM; ++j) acc = fmaf(wp[j], hp[(size_t)j * DIN], acc);
    size_t o = (size_t)bi * DIN + d;
    hinF[o] = acc;
    split_store(acc, &hinH[o], &hinL[o]);
}

__global__ __launch_bounds__(256) void colsum_k(const float* __restrict__ h,
                                                const float* __restrict__ W,
                                                float* __restrict__ houtF,
                                                ushort_t* __restrict__ houtH,
                                                ushort_t* __restrict__ houtL) {
    int d = blockIdx.x * 256 + threadIdx.x;
    int bj = blockIdx.y;  // b*S + j
    int b = bj / SDIM;
    int j = bj - b * SDIM;
    const float* hp = h + ((size_t)(b * SDIM) * SDIM + j) * DIN + d;
    const float* wp = W + (size_t)(b * SDIM) * SDIM + j;
    float acc = 0.f;
#pragma unroll 8
    for (int i = 0; i < SDIM; ++i)
        acc = fmaf(wp[(size_t)i * SDIM], hp[(size_t)i * SDIM * DIN], acc);
    size_t o = (size_t)bj * DIN + d;
    houtF[o] = acc;
    split_store(acc, &houtH[o], &houtL[o]);
}

// ---------------------------------------------------------------------------
// sem stencil; output split bf16 hi/lo (feeds gate GEMM A operand)
// ---------------------------------------------------------------------------
__global__ __launch_bounds__(256) void sem_k(const float* __restrict__ h,
                                             const float* __restrict__ a_simi,
                                             const float* __restrict__ t_simi,
                                             ushort_t* __restrict__ semH,
                                             ushort_t* __restrict__ semL) {
    int idx = blockIdx.x * 256 + threadIdx.x;  // < NROWS*192
    int d4 = idx % 192;
    int m = idx / 192;
    int j = m % SDIM;
    int r = m / SDIM;
    int i = r % SDIM;
    int b = r / SDIM;
    const float4* h4 = (const float4*)h;
    float4 acc = h4[(size_t)m * 192 + d4];
    if (j > 0) {
        float t = t_simi[b * SDIM + j - 1];
        float4 v = h4[(size_t)(m - 1) * 192 + d4];
        acc.x = fmaf(t, v.x, acc.x); acc.y = fmaf(t, v.y, acc.y);
        acc.z = fmaf(t, v.z, acc.z); acc.w = fmaf(t, v.w, acc.w);
    }
    if (j < SDIM - 1) {
        float t = t_simi[b * SDIM + j + 1];
        float4 v = h4[(size_t)(m + 1) * 192 + d4];
        acc.x = fmaf(t, v.x, acc.x); acc.y = fmaf(t, v.y, acc.y);
        acc.z = fmaf(t, v.z, acc.z); acc.w = fmaf(t, v.w, acc.w);
    }
    if (i > 0) {
        float a = a_simi[b * SDIM + i - 1];
        float4 v = h4[(size_t)(m - SDIM) * 192 + d4];
        acc.x = fmaf(a, v.x, acc.x); acc.y = fmaf(a, v.y, acc.y);
        acc.z = fmaf(a, v.z, acc.z); acc.w = fmaf(a, v.w, acc.w);
    }
    if (i < SDIM - 1) {
        float a = a_simi[b * SDIM + i + 1];
        float4 v = h4[(size_t)(m + SDIM) * 192 + d4];
        acc.x = fmaf(a, v.x, acc.x); acc.y = fmaf(a, v.y, acc.y);
        acc.z = fmaf(a, v.z, acc.z); acc.w = fmaf(a, v.w, acc.w);
    }
    size_t o = (size_t)m * DIN + d4 * 4;
    ushort_t hh[4], ll[4];
    float vv[4] = {acc.x, acc.y, acc.z, acc.w};
#pragma unroll
    for (int e = 0; e < 4; ++e) {
        hh[e] = f2bf(vv[e]);
        ll[e] = f2bf(vv[e] - bf2f(hh[e]));
    }
    *(ushort4*)&semH[o] = make_ushort4(hh[0], hh[1], hh[2], hh[3]);
    *(ushort4*)&semL[o] = make_ushort4(ll[0], ll[1], ll[2], ll[3]);
}

// ---------------------------------------------------------------------------
// Split-bf16 MFMA GEMM: C(MxN) = (AH+AL)(MxK) @ (BH+BL)^T-stored(NxK)
// 3 MFMA per pair (hh + hl + lh), fp32 accum.
// Tile 256x256, BK=32, 512 threads = 8 waves (4m x 2n); wave out = 64x128.
// 128 KB dynamic LDS, DOUBLE-buffered global_load_lds prefetch, 1 barrier/iter.
// Chunk layout [4 kslice][16 row][16B]: staging and frag reads both
// base + lane*16 -> 0 bank conflicts (verified r5).
// EPI 0: C = acc + bias  (fp32 out)
// EPI 1: gate fusion (bias = gate_b): logit = acc + Pin + Pout + bias;
//        C = g*sem + (1-g)*syn + hprev  -> XH/XL bf16 hi/lo
// ---------------------------------------------------------------------------
template <int EPI>
__global__ __launch_bounds__(512) void gemm_mfma(
    const ushort_t* __restrict__ AH, const ushort_t* __restrict__ AL,
    const ushort_t* __restrict__ BH, const ushort_t* __restrict__ BL,  // [N][K]
    int M, int N, int K, int nbx,
    float* __restrict__ C, const float* __restrict__ bias,
    ushort_t* __restrict__ XH, ushort_t* __restrict__ XL,
    const float* __restrict__ Pin, const float* __restrict__ Pout,
    const float* __restrict__ hin, const float* __restrict__ hout,
    const float* __restrict__ hprev) {
    extern __shared__ __align__(16) char smem[];
    // per buffer (64 KB): [Ah 16K][Al 16K][Bh 16K][Bl 16K]; chunk = 1024 B
    ushort_t* SM = (ushort_t*)smem;

    // bijective XCD-aware swizzle (m204 form; works for any nwg)
    const int nwg = gridDim.x;
    const int orig = blockIdx.x;
    const int qq = nwg >> 3, rr = nwg & 7;
    const int xcd = orig & 7, sidx = orig >> 3;
    const int swz = (xcd < rr ? xcd * (qq + 1) : rr * (qq + 1) + (xcd - rr) * qq) + sidx;
    const int bx = swz % nbx;
    const int by = swz / nbx;
    const int bm = by * 256, bn = bx * 256;

    const int tid = threadIdx.x;
    const int wave = tid >> 6, lane = tid & 63;
    const int lq = lane & 15;            // row within 16-row chunk
    const int lg = lane >> 4;            // k-slice (8 ushorts)
    const int wm = wave >> 1, wn = wave & 1;   // 4m x 2n wave grid

    f32x4 acc[4][8];
#pragma unroll
    for (int a = 0; a < 4; ++a)
#pragma unroll
        for (int b = 0; b < 8; ++b) acc[a][b] = (f32x4){0.f, 0.f, 0.f, 0.f};

    const int nt = K >> 5;  // K/32 tiles

    // per-wave staging: A chunks {wave, wave+8} hi+lo, B chunks {wave, wave+8} hi+lo
    // buffer base (ushorts): buf*32768; Al +8192, Bh +16384, Bl +24576
#define STAGE(buf, k0)                                                              \
    {                                                                               \
        _Pragma("unroll") for (int cc = 0; cc < 2; ++cc) {                          \
            const int c = wave + cc * 8;                                            \
            const int row = c * 16 + lq;                                            \
            const size_t ga = (size_t)(bm + row) * K + (k0) + lg * 8;               \
            const size_t gb = (size_t)(bn + row) * K + (k0) + lg * 8;               \
            ushort_t* base = SM + (buf) * 32768 + c * 512;                          \
            load_lds16(AH + ga, base);                                              \
            load_lds16(AL + ga, base + 8192);                                       \
            load_lds16(BH + gb, base + 16384);                                      \
            load_lds16(BL + gb, base + 24576);                                      \
        }                                                                           \
    }

    STAGE(0, 0);
    __syncthreads();

    int cur = 0;
    for (int t = 0; t < nt; ++t) {
        if (t + 1 < nt) STAGE(cur ^ 1, (t + 1) * 32);

        const ushort_t* Ah = SM + cur * 32768;
        s16x8 ah[4], al[4];
#pragma unroll
        for (int f = 0; f < 4; ++f) {
            const int cA = (wm * 4 + f) * 512 + lane * 8;
            ah[f] = *(const s16x8*)&Ah[cA];
            al[f] = *(const s16x8*)&Ah[8192 + cA];
        }
        __builtin_amdgcn_s_setprio(1);
#pragma unroll
        for (int nf = 0; nf < 8; ++nf) {
            const int cB = (wn * 8 + nf) * 512 + lane * 8;
            s16x8 bh = *(const s16x8*)&Ah[16384 + cB];
            s16x8 bl = *(const s16x8*)&Ah[24576 + cB];
#pragma unroll
            for (int mf = 0; mf < 4; ++mf) {
                acc[mf][nf] = __builtin_amdgcn_mfma_f32_16x16x32_bf16(ah[mf], bh, acc[mf][nf], 0, 0, 0);
                acc[mf][nf] = __builtin_amdgcn_mfma_f32_16x16x32_bf16(ah[mf], bl, acc[mf][nf], 0, 0, 0);
                acc[mf][nf] = __builtin_amdgcn_mfma_f32_16x16x32_bf16(al[mf], bh, acc[mf][nf], 0, 0, 0);
            }
        }
        __builtin_amdgcn_s_setprio(0);
        __syncthreads();  // drains prefetch vmcnt + syncs buffer reuse
        cur ^= 1;
    }
#undef STAGE

    // epilogue. C/D layout (HW-verified m89): col = lane&15, row = (lane>>4)*4 + reg
#pragma unroll
    for (int mf = 0; mf < 4; ++mf) {
#pragma unroll
        for (int jj = 0; jj < 4; ++jj) {
            const int gr = bm + wm * 64 + mf * 16 + lg * 4 + jj;
            int ri = 0, rj = 0;
            if (EPI == 1) {
                const int b_ = gr / 9216;
                const int rem = gr - b_ * 9216;
                const int i_ = rem / 96;
                const int j_ = rem - i_ * 96;
                ri = (b_ * 96 + i_) * 768;
                rj = (b_ * 96 + j_) * 768;
            }
#pragma unroll
            for (int nf = 0; nf < 8; ++nf) {
                const int gc = bn + wn * 128 + nf * 16 + lq;
                float v = acc[mf][nf][jj];
                if (EPI == 0) {
                    if (bias != nullptr) v += bias[gc];
                    C[(size_t)gr * N + gc] = v;
                } else {
                    const float gte = sigmoid_f(v + Pin[ri + gc] + Pout[rj + gc] + bias[gc]);
                    const float syn = hin[ri + gc] + hout[rj + gc];
                    const size_t o = (size_t)gr * 768 + gc;
                    const float sem = bf2f(AH[o]) + bf2f(AL[o]);
                    const float x = fmaf(gte, sem - syn, syn) + hprev[o];
                    split_store(x, &XH[o], &XL[o]);
                }
            }
        }
    }
}

// ---------------------------------------------------------------------------
// T5 layernorm (+relu): out = max(0, x * rsqrt(mean(x^2)+eps) * w), per row
// ---------------------------------------------------------------------------
template <int D>
__global__ __launch_bounds__(256) void norm_relu_k(const float* __restrict__ Y,
                                                   const float* __restrict__ w,
                                                   float* __restrict__ out) {
    constexpr int E = D / 256;
    int row = blockIdx.x;
    int tid = threadIdx.x;
    float v[E];
    float ss = 0.f;
#pragma unroll
    for (int e = 0; e < E; ++e) {
        v[e] = Y[(size_t)row * D + e * 256 + tid];
        ss = fmaf(v[e], v[e], ss);
    }
#pragma unroll
    for (int off = 32; off >= 1; off >>= 1) ss += __shfl_down(ss, off);
    __shared__ float red[4];
    int lane = tid & 63;
    int wid = tid >> 6;
    if (lane == 0) red[wid] = ss;
    __syncthreads();
    float tot = red[0] + red[1] + red[2] + red[3];
    float scale = rsqrtf(tot / (float)D + 1e-12f);
#pragma unroll
    for (int e = 0; e < E; ++e) {
        float o = v[e] * scale * w[e * 256 + tid];
        out[(size_t)row * D + e * 256 + tid] = fmaxf(o, 0.f);
    }
}

// ---------------------------------------------------------------------------
// launch
// ---------------------------------------------------------------------------
extern "C" void kernel_launch(void* const* d_in, const int* in_sizes, int n_in,
                              void* d_out, int out_size, void* d_ws, size_t ws_size,
                              hipStream_t stream) {
    (void)in_sizes; (void)n_in; (void)out_size; (void)ws_size;

    // allow 128 KB dynamic LDS (idempotent; host-side; graph-capture safe)
    hipFuncSetAttribute((const void*)&gemm_mfma<0>,
                        hipFuncAttributeMaxDynamicSharedMemorySize, 131072);
    hipFuncSetAttribute((const void*)&gemm_mfma<1>,
                        hipFuncAttributeMaxDynamicSharedMemorySize, 131072);

    const float* table = (const float*)d_in[0];
    const float* a_simi = (const float*)d_in[1];
    const float* t_simi = (const float*)d_in[2];
    const float* dep_matrix = (const float*)d_in[3];
    const int* dep_types = (const int*)d_in[4];
    const float* d1w = (const float*)d_in[5];
    const float* d1b = (const float*)d_in[6];
    const float* d2w = (const float*)d_in[7];
    const float* d2b = (const float*)d_in[8];
    const float* dep_emb = (const float*)d_in[9];
    const float* att_w = (const float*)d_in[10];
    const float* att_b = (const float*)d_in[11];
    const float* gate_w = (const float*)d_in[12];
    const float* gate_b = (const float*)d_in[13];
    const float* nw1 = (const float*)d_in[14];
    const float* nw2 = (const float*)d_in[15];
    float* out = (float*)d_out;

    // ---- workspace layout (all 16B-aligned offsets) ----
    char* ws = (char*)d_ws;
    size_t off = 0;
    float* Wd = (float*)(ws + off); off += 147456;
    float* hinF = (float*)(ws + off); off += 1179648;
    float* houtF = (float*)(ws + off); off += 1179648;
    float* Pfull = (float*)(ws + off); off += 2359296;          // 768 x 768 fp32
    ushort_t* hioH = (ushort_t*)(ws + off); off += 1179648;     // 768 x 768 bf16 (hin 0..383, hout 384..767)
    ushort_t* hioL = (ushort_t*)(ws + off); off += 1179648;
    ushort_t* GtopTH = (ushort_t*)(ws + off); off += 1179648;
    ushort_t* GtopTL = (ushort_t*)(ws + off); off += 1179648;
    ushort_t* GbotTH = (ushort_t*)(ws + off); off += 1179648;
    ushort_t* GbotTL = (ushort_t*)(ws + off); off += 1179648;
    ushort_t* D1TH = (ushort_t*)(ws + off); off += 1179648;
    ushort_t* D1TL = (ushort_t*)(ws + off); off += 1179648;
    ushort_t* D2TH = (ushort_t*)(ws + off); off += 393216;
    ushort_t* D2TL = (ushort_t*)(ws + off); off += 393216;
    char* P1 = ws + off; off += 113246208;  // sem1 H/L -> Y1 fp32 -> X2 H/L
    char* P2 = ws + off; off += 113246208;  // X1 H/L -> sem2 H/L
    char* P3 = ws + off; off += 113246208;  // h1 fp32 -> Y2 fp32

    const size_t HALF = 56623104;  // 36864*768*2 bytes
    ushort_t* S1H = (ushort_t*)P1;            ushort_t* S1L = (ushort_t*)(P1 + HALF);
    ushort_t* X1H = (ushort_t*)P2;            ushort_t* X1L = (ushort_t*)(P2 + HALF);
    float* Y1 = (float*)P1;
    float* h1 = (float*)P3;
    ushort_t* S2H = (ushort_t*)P2;            ushort_t* S2L = (ushort_t*)(P2 + HALF);
    ushort_t* X2H = (ushort_t*)P1;            ushort_t* X2L = (ushort_t*)(P1 + HALF);
    float* Y2 = (float*)P3;

    float* Pin = Pfull;                       // rows 0..383
    float* Pout = Pfull + (size_t)BSROWS * DIN;  // rows 384..767

    const dim3 blk(256);
    const dim3 blk512(512);
    const size_t LDSB = 131072;  // 128 KB dynamic LDS (2 x 64 KB buffers)
    const dim3 gSplit768(3, 768);
    const dim3 gSplit256(3, 256);
    const dim3 gRS(DIN / 256, BSROWS);
    const int gSem = (NROWS * (DIN / 4)) / 256;
    const int gBig = (NROWS / 256) * (DIN / 256);   // 144*3 = 432
    const int gD2g = (NROWS / 256) * (DOUT / 256);  // 144*1 = 144
    const int gP = (2 * BSROWS / 256) * (DIN / 256);  // 3*3 = 9

    // dep weights + weight split/transpose (weights: [K][N] -> [N][K] hi/lo)
    depw_k<<<NROWS / 256, blk, 0, stream>>>(dep_types, dep_matrix, dep_emb, att_w, att_b, Wd);
    splitT_k<<<gSplit768, blk, 0, stream>>>(gate_w, GtopTH, GtopTL, DIN, DIN);
    splitT_k<<<gSplit768, blk, 0, stream>>>(gate_w + (size_t)DIN * DIN, GbotTH, GbotTL, DIN, DIN);
    splitT_k<<<gSplit768, blk, 0, stream>>>(d1w, D1TH, D1TL, DIN, DIN);
    splitT_k<<<gSplit256, blk, 0, stream>>>(d2w, D2TH, D2TL, DIN, DOUT);

    // ---------------- layer 1 (input: table) ----------------
    rowsum_k<<<gRS, blk, 0, stream>>>(table, Wd, hinF, hioH, hioL);
    colsum_k<<<gRS, blk, 0, stream>>>(table, Wd, houtF, hioH + (size_t)BSROWS * DIN,
                                      hioL + (size_t)BSROWS * DIN);
    sem_k<<<gSem, blk, 0, stream>>>(table, a_simi, t_simi, S1H, S1L);
    // fused P GEMM: [hin; hout] (768 rows) @ Wbot -> Pfull
    gemm_mfma<0><<<gP, blk512, LDSB, stream>>>(hioH, hioL, GbotTH, GbotTL, 2 * BSROWS, DIN, DIN, DIN / 256,
                                               Pfull, nullptr, nullptr, nullptr, nullptr, nullptr, nullptr, nullptr, nullptr);
    // gate GEMM + fusion -> X1 (bias = gate_b applied in epilogue)
    gemm_mfma<1><<<gBig, blk512, LDSB, stream>>>(S1H, S1L, GtopTH, GtopTL, NROWS, DIN, DIN, DIN / 256,
                                                 nullptr, gate_b, X1H, X1L, Pin, Pout, hinF, houtF, table);
    // dense1 + bias -> Y1
    gemm_mfma<0><<<gBig, blk512, LDSB, stream>>>(X1H, X1L, D1TH, D1TL, NROWS, DIN, DIN, DIN / 256,
                                                 Y1, d1b, nullptr, nullptr, nullptr, nullptr, nullptr, nullptr, nullptr);
    norm_relu_k<DIN><<<NROWS, blk, 0, stream>>>(Y1, nw1, h1);

    // ---------------- layer 2 (input: h1) ----------------
    rowsum_k<<<gRS, blk, 0, stream>>>(h1, Wd, hinF, hioH, hioL);
    colsum_k<<<gRS, blk, 0, stream>>>(h1, Wd, houtF, hioH + (size_t)BSROWS * DIN,
                                      hioL + (size_t)BSROWS * DIN);
    sem_k<<<gSem, blk, 0, stream>>>(h1, a_simi, t_simi, S2H, S2L);
    gemm_mfma<0><<<gP, blk512, LDSB, stream>>>(hioH, hioL, GbotTH, GbotTL, 2 * BSROWS, DIN, DIN, DIN / 256,
                                               Pfull, nullptr, nullptr, nullptr, nullptr, nullptr, nullptr, nullptr, nullptr);
    gemm_mfma<1><<<gBig, blk512, LDSB, stream>>>(S2H, S2L, GtopTH, GtopTL, NROWS, DIN, DIN, DIN / 256,
                                                 nullptr, gate_b, X2H, X2L, Pin, Pout, hinF, houtF, h1);
    // dense2 + bias -> Y2 (N=256)
    gemm_mfma<0><<<gD2g, blk512, LDSB, stream>>>(X2H, X2L, D2TH, D2TL, NROWS, DOUT, DIN, DOUT / 256,
                                                 Y2, d2b, nullptr, nullptr, nullptr, nullptr, nullptr, nullptr, nullptr);
    norm_relu_k<DOUT><<<NROWS, blk, 0, stream>>>(Y2, nw2, out);
}